// Round 6
// baseline (161.908 us; speedup 1.0000x reference)
//
#include <hip/hip_runtime.h>
#include <hip/hip_bf16.h>

#define DIMC 1024
#define HEADS 16
#define HD 64
#define BATCH 2
#define SEQ 2048

typedef __bf16 bf16;
typedef __bf16 bf16x4 __attribute__((ext_vector_type(4)));
typedef __bf16 bf16x8 __attribute__((ext_vector_type(8)));
typedef float f32x4 __attribute__((ext_vector_type(4)));

typedef const __attribute__((address_space(1))) void* gas_t;
typedef __attribute__((address_space(3))) void* las_t;

__device__ inline f32x4 mfma_bf16(bf16x8 a, bf16x8 b, f32x4 c) {
    return __builtin_amdgcn_mfma_f32_16x16x32_bf16(a, b, c, 0, 0, 0);
}

// store 8 bf16 to LDS as two b64 (row strides are 8B- but not 16B-aligned)
__device__ inline void st8(bf16* p, bf16x8 v) {
    *(bf16x4*)p       = *(bf16x4*)&v;
    *(bf16x4*)(p + 4) = *((bf16x4*)&v + 1);
}
// load one MFMA operand fragment: elements 0..3 at k, 4..7 at k+16
__device__ inline bf16x8 ld_frag(const bf16* p) {
    bf16x8 r;
    *(bf16x4*)&r       = *(const bf16x4*)p;
    *((bf16x4*)&r + 1) = *(const bf16x4*)(p + 16);
    return r;
}
// fragment read from a linear [*, 64] LDS tile with XOR-swizzled chunks:
// rowp = &tile[row*64]; cb = byte col (kk*64 + lg*8); sw = (row&7)<<4
__device__ inline bf16x8 ld_frag_s(const bf16* rowp, int cb, int sw) {
    bf16x8 r;
    *(bf16x4*)&r       = *(const bf16x4*)((const char*)rowp + ((cb) ^ sw));
    *((bf16x4*)&r + 1) = *(const bf16x4*)((const char*)rowp + ((cb + 32) ^ sw));
    return r;
}

// ---------------- prep: sanitize+clip x -> bf16 ----------------
__global__ __launch_bounds__(256) void k_prep_x(const float* __restrict__ x,
                                                bf16* __restrict__ xb) {
    int i = blockIdx.x * 256 + threadIdx.x;
    float4 v = ((const float4*)x)[i];
    float a[4] = {v.x, v.y, v.z, v.w};
    bf16x4 o;
#pragma unroll
    for (int j = 0; j < 4; ++j) {
        float f = a[j];
        f = __builtin_isfinite(f) ? fminf(fmaxf(f, -10000.f), 10000.f) : 0.f;
        o[j] = (bf16)f;
    }
    ((bf16x4*)xb)[i] = o;
}

__global__ __launch_bounds__(256) void k_cast(const float* __restrict__ a,
                                              bf16* __restrict__ o) {
    int i = blockIdx.x * 256 + threadIdx.x;
    float4 v = ((const float4*)a)[i];
    bf16x4 r = {(bf16)v.x, (bf16)v.y, (bf16)v.z, (bf16)v.w};
    ((bf16x4*)o)[i] = r;
}

// ---------------- GEMM: C[M][N] = A[M][K] * Bt[N][K]^T ----------------
// m97 structure: 128x128 tile, BK=64, linear LDS + global_load_lds width=16,
// XOR-swizzled chunks (pre-swizzled global source, swizzled ds_read).
// 4 waves (2x2), each wave 64x64 = 4x4 frags of 16x16x32 MFMA.
template <bool OUT_BF16, bool BIAS, bool SANITIZE>
__global__ __launch_bounds__(256) void k_gemm_bt(const bf16* __restrict__ A,
                                                 const bf16* __restrict__ Bt,
                                                 void* __restrict__ Cv,
                                                 const float* __restrict__ bias,
                                                 int N, int K) {
    __shared__ alignas(16) bf16 As[128 * 64];
    __shared__ alignas(16) bf16 Bs[128 * 64];
    const int t = threadIdx.x;
    const int m0 = blockIdx.y * 128, n0 = blockIdx.x * 128;
    const int w = t >> 6, lane = t & 63;
    const int wm = (w >> 1) * 64, wn = (w & 1) * 64;
    const int lr = lane & 15, lg = lane >> 4;
    // staging coords: each wave-instr covers 8 rows x 64 cols (1KB).
    // lane l -> LDS row l>>3, chunk l&7; global source chunk pre-swizzled.
    const int srow = lane >> 3;                       // 0..7 within group
    const int scol = ((lane & 7) ^ srow) * 8;         // element col (XOR swz)
    const int sw = (lr & 7) << 4;                     // read-side swizzle

    f32x4 acc[4][4];
#pragma unroll
    for (int i = 0; i < 4; ++i)
#pragma unroll
        for (int j = 0; j < 4; ++j) acc[i][j] = 0.0f;

    for (int k0 = 0; k0 < K; k0 += 64) {
#pragma unroll
        for (int i = 0; i < 4; ++i) {
            int rg = w * 32 + i * 8;                  // group base row
            __builtin_amdgcn_global_load_lds(
                (gas_t)(A + (size_t)(m0 + rg + srow) * K + k0 + scol),
                (las_t)(As + rg * 64), 16, 0, 0);
            __builtin_amdgcn_global_load_lds(
                (gas_t)(Bt + (size_t)(n0 + rg + srow) * K + k0 + scol),
                (las_t)(Bs + rg * 64), 16, 0, 0);
        }
        __syncthreads();
#pragma unroll
        for (int kk = 0; kk < 2; ++kk) {
            const int cb = kk * 64 + lg * 8;
            bf16x8 af[4], bfr[4];
#pragma unroll
            for (int mi = 0; mi < 4; ++mi)
                af[mi] = ld_frag_s(&As[(wm + mi * 16 + lr) * 64], cb, sw);
#pragma unroll
            for (int ni = 0; ni < 4; ++ni)
                bfr[ni] = ld_frag_s(&Bs[(wn + ni * 16 + lr) * 64], cb, sw);
#pragma unroll
            for (int mi = 0; mi < 4; ++mi)
#pragma unroll
                for (int ni = 0; ni < 4; ++ni)
                    acc[mi][ni] = mfma_bf16(af[mi], bfr[ni], acc[mi][ni]);
        }
        __syncthreads();
    }
    // epilogue; C/D layout: col = lane&15, row = (lane>>4)*4 + reg
#pragma unroll
    for (int mi = 0; mi < 4; ++mi) {
#pragma unroll
        for (int ni = 0; ni < 4; ++ni) {
            int col = n0 + wn + ni * 16 + lr;
            float bval = BIAS ? bias[col] : 0.f;
#pragma unroll
            for (int r = 0; r < 4; ++r) {
                int row = m0 + wm + mi * 16 + lg * 4 + r;
                float v = acc[mi][ni][r];
                if (SANITIZE) v = __builtin_isfinite(v) ? v : 0.f;
                v += bval;
                if (OUT_BF16)
                    ((bf16*)Cv)[(size_t)row * N + col] = (bf16)v;
                else
                    ((float*)Cv)[(size_t)row * N + col] = v;
            }
        }
    }
}

// ---------------- postprocess: rmsnorm + rope, v transpose ----------------
// grid (32 lblocks, 16 heads, 2 batch) x 256 threads
__global__ __launch_bounds__(256) void k_post(const bf16* __restrict__ qkvb,
                                              const float* __restrict__ pe,
                                              const float* __restrict__ q_scale,
                                              const float* __restrict__ k_scale,
                                              bf16* __restrict__ qb,
                                              bf16* __restrict__ kb,
                                              bf16* __restrict__ vt) {
    const int lb = blockIdx.x, h = blockIdx.y, b = blockIdx.z;
    const int t = threadIdx.x;
    const int row = t >> 2, sub = t & 3;  // 64 rows x 4 lanes each
    const int l = lb * 64 + row;
    const int d0 = sub * 16;
    const size_t rowbase = ((size_t)(b * SEQ + l)) * (3 * DIMC) + h * HD;
    const size_t bh = (size_t)(b * HEADS + h);

#pragma unroll
    for (int qk = 0; qk < 2; ++qk) {
        const bf16* src = qkvb + rowbase + qk * DIMC + d0;
        const float* sc = qk ? k_scale : q_scale;
        bf16x8 v0 = *(const bf16x8*)src;
        bf16x8 v1 = *(const bf16x8*)(src + 8);
        float vals[16];
        float ss = 0.f;
#pragma unroll
        for (int j = 0; j < 8; ++j) {
            vals[j] = (float)v0[j];
            vals[8 + j] = (float)v1[j];
        }
#pragma unroll
        for (int j = 0; j < 16; ++j) ss += vals[j] * vals[j];
        ss += __shfl_xor(ss, 1, 64);
        ss += __shfl_xor(ss, 2, 64);
        float rms = rsqrtf(ss * (1.f / 64.f) + 1e-6f);
        // fold attention scale D^-0.5 and log2(e) into q
        const float outscale = qk ? 1.0f : 0.125f * 1.44269504088896340736f;
        bf16 ob[16];
#pragma unroll
        for (int j = 0; j < 16; j += 2) {
            int d = d0 + j;
            float e0 = vals[j] * rms * sc[d];
            float e1 = vals[j + 1] * rms * sc[d + 1];
            float4 pv = *(const float4*)(pe + (size_t)l * 128 + (d >> 1) * 4);
            float o0 = pv.x * e0 + pv.y * e1;
            float o1 = pv.z * e0 + pv.w * e1;
            ob[j] = (bf16)(o0 * outscale);
            ob[j + 1] = (bf16)(o1 * outscale);
        }
        bf16* dst = (qk ? kb : qb) + (bh * SEQ + l) * HD + d0;
        *(bf16x8*)dst = *(bf16x8*)&ob[0];
        *(bf16x8*)(dst + 8) = *(bf16x8*)&ob[8];
    }

    // V: cast + transpose to [B,H,D,L] via LDS
    __shared__ bf16 vlds[64][68];
    {
        const bf16* src = qkvb + rowbase + 2 * DIMC + d0;
        bf16x8 v0 = *(const bf16x8*)src;
        bf16x8 v1 = *(const bf16x8*)(src + 8);
        st8(&vlds[row][d0], v0);
        st8(&vlds[row][d0 + 8], v1);
    }
    __syncthreads();
    {
        const int d = t >> 2, c0 = (t & 3) * 16;
        bf16 ob[16];
#pragma unroll
        for (int j = 0; j < 16; ++j) ob[j] = vlds[c0 + j][d];
        bf16* dst = vt + (bh * HD + d) * SEQ + lb * 64 + c0;
        *(bf16x8*)dst = *(bf16x8*)&ob[0];
        *(bf16x8*)(dst + 8) = *(bf16x8*)&ob[8];
    }
}

// ---------------- flash attention (split-KV within block) ----------------
// grid (L/64 q-tiles, B*H), 512 threads = 8 waves.
// Waves 0-3: q rows (w)*16 of a 64-row tile, KV half [0, SEQ/2).
// Waves 4-7: same q rows, KV half [SEQ/2, SEQ). Combine in LDS at the end.
// Per wave: swapped QK^T (S^T = mfma(K,Q)), softmax in-lane, register P,
// PV as O^T = mfma(V^T, P^T); l via ones-MFMA; defer-max THR=8 (exp2 dom).
// Single-buffered K/V per half, reg-prefetch (T14), 2 barriers/tile.
__global__ __launch_bounds__(512, 6) void k_attn(const bf16* __restrict__ Q,
                                                 const bf16* __restrict__ Kb,
                                                 const bf16* __restrict__ Vt,
                                                 bf16* __restrict__ O) {
    __shared__ alignas(16) bf16 smem[4 * 64 * 68];  // [K0|K1|V0|V1] = 34816 B
    const int qt = blockIdx.x, bh = blockIdx.y;
    const int b = bh >> 4, h = bh & 15;
    const int t = threadIdx.x, w = t >> 6, lane = t & 63;
    const int lr = lane & 15, lg = lane >> 4;
    const int wq = w & 3;            // q sub-tile (16 rows)
    const int half = w >> 2;         // KV half this wave consumes
    const size_t baseQK = (size_t)bh * SEQ * HD;
    const size_t baseVt = (size_t)bh * HD * SEQ;
    const int NT = SEQ / 2 / 64;     // tiles per half

    bf16* Kmy = smem + half * 4352;          // 64x68
    bf16* Vmy = smem + 8704 + half * 4352;   // 64x68 (Vt tile: [d][key])

    // Q fragments straight from global (lane-private; 4 x 8B loads)
    const bf16* qp = Q + baseQK + (size_t)(qt * 64 + wq * 16 + lr) * HD;
    bf16x8 qf0 = ld_frag(qp + lg * 4);
    bf16x8 qf1 = ld_frag(qp + 32 + lg * 4);

    // staging coords: 512 threads cover one 64x64 tile (8 el each)
    const int sr = t >> 3, scol = (t & 7) * 8;
    const bf16* kg0 = Kb + baseQK + (size_t)sr * HD + scol;            // +half*1024*HD +kt*64*HD
    const bf16* vg0 = Vt + baseVt + (size_t)sr * SEQ + scol;           // +half*1024 +kt*64
    // prologue: stage tile 0 of both halves
    {
        bf16x8 k0 = *(const bf16x8*)(kg0);
        bf16x8 k1 = *(const bf16x8*)(kg0 + (size_t)(SEQ / 2) * HD);
        bf16x8 v0 = *(const bf16x8*)(vg0);
        bf16x8 v1 = *(const bf16x8*)(vg0 + SEQ / 2);
        st8(smem + sr * 68 + scol, k0);
        st8(smem + 4352 + sr * 68 + scol, k1);
        st8(smem + 8704 + sr * 68 + scol, v0);
        st8(smem + 13056 + sr * 68 + scol, v1);
    }
    __syncthreads();

    bf16x8 ones;
#pragma unroll
    for (int j = 0; j < 8; ++j) ones[j] = (bf16)1.0f;

    f32x4 oacc[4];
#pragma unroll
    for (int i = 0; i < 4; ++i) oacc[i] = 0.0f;
    f32x4 lacc = 0.0f;
    float m_s = -1e30f;

    for (int kt = 0; kt < NT; ++kt) {
        // issue next tile's global loads early (hidden under compute)
        bf16x8 k0r, k1r, v0r, v1r;
        const bool pf = (kt + 1) < NT;
        if (pf) {
            const bf16* kg = kg0 + (size_t)((kt + 1) * 64) * HD;
            const bf16* vg = vg0 + (kt + 1) * 64;
            k0r = *(const bf16x8*)(kg);
            k1r = *(const bf16x8*)(kg + (size_t)(SEQ / 2) * HD);
            v0r = *(const bf16x8*)(vg);
            v1r = *(const bf16x8*)(vg + SEQ / 2);
        }
        // QK^T on current tile (my half)
        __builtin_amdgcn_s_setprio(1);
        f32x4 s[4];
#pragma unroll
        for (int nk = 0; nk < 4; ++nk) {
            f32x4 a = 0.0f;
            a = mfma_bf16(ld_frag(Kmy + (nk * 16 + lr) * 68 + lg * 4), qf0, a);
            a = mfma_bf16(ld_frag(Kmy + (nk * 16 + lr) * 68 + 32 + lg * 4), qf1, a);
            s[nk] = a;
        }
        __builtin_amdgcn_s_setprio(0);
        // row max: 16 in-lane + 2 shfls (q pre-scaled into exp2 domain)
        float tm = fmaxf(fmaxf(s[0][0], s[0][1]), fmaxf(s[0][2], s[0][3]));
#pragma unroll
        for (int nk = 1; nk < 4; ++nk)
            tm = fmaxf(tm, fmaxf(fmaxf(s[nk][0], s[nk][1]),
                                 fmaxf(s[nk][2], s[nk][3])));
        tm = fmaxf(tm, __shfl_xor(tm, 16, 64));
        tm = fmaxf(tm, __shfl_xor(tm, 32, 64));
        // defer-max: only rescale when some row grew past THR=8
        if (!__all(tm <= m_s + 8.f)) {
            float mnew = fmaxf(m_s, tm);
            float alpha = exp2f(m_s - mnew);
            m_s = mnew;
#pragma unroll
            for (int nd = 0; nd < 4; ++nd)
#pragma unroll
                for (int r2 = 0; r2 < 4; ++r2) oacc[nd][r2] *= alpha;
#pragma unroll
            for (int r2 = 0; r2 < 4; ++r2) lacc[r2] *= alpha;
        }
        // P (bounded by 2^8) packed straight into A-frag layout
        bf16x8 pa0, pa1;
#pragma unroll
        for (int j = 0; j < 4; ++j) {
            pa0[j]     = (bf16)exp2f(s[0][j] - m_s);
            pa0[4 + j] = (bf16)exp2f(s[1][j] - m_s);
            pa1[j]     = (bf16)exp2f(s[2][j] - m_s);
            pa1[4 + j] = (bf16)exp2f(s[3][j] - m_s);
        }
        __builtin_amdgcn_s_setprio(1);
        // l row-sum via ones-MFMA (lands in col q = lane&15, all regs equal)
        lacc = mfma_bf16(ones, pa0, lacc);
        lacc = mfma_bf16(ones, pa1, lacc);
#pragma unroll
        for (int nd = 0; nd < 4; ++nd) {
            oacc[nd] = mfma_bf16(ld_frag(Vmy + (nd * 16 + lr) * 68 + lg * 4), pa0, oacc[nd]);
            oacc[nd] = mfma_bf16(ld_frag(Vmy + (nd * 16 + lr) * 68 + 32 + lg * 4), pa1, oacc[nd]);
        }
        __builtin_amdgcn_s_setprio(0);
        __syncthreads();          // all waves done reading current tiles
        if (pf) {
            st8(smem + sr * 68 + scol, k0r);
            st8(smem + 4352 + sr * 68 + scol, k1r);
            st8(smem + 8704 + sr * 68 + scol, v0r);
            st8(smem + 13056 + sr * 68 + scol, v1r);
            __syncthreads();      // writes visible before next compute
        }
    }
    // combine halves: waves 4-7 publish (O^T, m, l); waves 0-3 merge + write
    float* xf = (float*)smem;     // 4*64*18*4B = 18432 B, aliases dead K/V
    if (w >= 4) {
        int slot = ((w - 4) * 64 + lane) * 18;
#pragma unroll
        for (int nd = 0; nd < 4; ++nd)
#pragma unroll
            for (int r2 = 0; r2 < 4; ++r2) xf[slot + nd * 4 + r2] = oacc[nd][r2];
        xf[slot + 16] = m_s;
        xf[slot + 17] = lacc[0];
    }
    __syncthreads();
    if (w < 4) {
        int slot = (w * 64 + lane) * 18;
        float m_b = xf[slot + 16], l_b = xf[slot + 17];
        float m_n = fmaxf(m_s, m_b);
        float aa = exp2f(m_s - m_n), ab = exp2f(m_b - m_n);
        float l_n = lacc[0] * aa + l_b * ab;
        float inv = 1.f / l_n;
        int q = qt * 64 + wq * 16 + lr;
#pragma unroll
        for (int nd = 0; nd < 4; ++nd) {
            bf16x4 ov;
#pragma unroll
            for (int r2 = 0; r2 < 4; ++r2) {
                float v = (oacc[nd][r2] * aa + xf[slot + nd * 4 + r2] * ab) * inv;
                v = fminf(fmaxf(v, -10000.f), 10000.f);
                ov[r2] = (bf16)v;
            }
            *(bf16x4*)(O + ((size_t)(b * SEQ + q)) * DIMC + h * HD + nd * 16 + lg * 4) = ov;
        }
    }
}

extern "C" void kernel_launch(void* const* d_in, const int* in_sizes, int n_in,
                              void* d_out, int out_size, void* d_ws, size_t ws_size,
                              hipStream_t stream) {
    const float* x = (const float*)d_in[0];
    const float* pe = (const float*)d_in[1];
    const float* qkv_w = (const float*)d_in[2];
    const float* q_scale = (const float*)d_in[3];
    const float* k_scale = (const float*)d_in[4];
    const float* proj_w = (const float*)d_in[5];
    const float* proj_b = (const float*)d_in[6];
    float* out = (float*)d_out;
    char* ws = (char*)d_ws;

    // workspace layout (64 MB total)
    bf16* xb = (bf16*)(ws);                              // 8 MB  [4096][1024]
    bf16* wqkv = (bf16*)(ws + (8u << 20));               // 6 MB  [3072][1024]
    bf16* wproj = (bf16*)(ws + (14u << 20));             // 2 MB  [1024][1024]
    bf16* qkvb = (bf16*)(ws + (16u << 20));              // 24 MB [4096][3072]
    bf16* ao = (bf16*)(ws + (16u << 20));                // 8 MB, overlays qkvb (dead)
    bf16* qb = (bf16*)(ws + (40u << 20));                // 8 MB  [B,H,L,D]
    bf16* kb = (bf16*)(ws + (48u << 20));                // 8 MB  [B,H,L,D]
    bf16* vt = (bf16*)(ws + (56u << 20));                // 8 MB  [B,H,D,L]

    k_prep_x<<<4096, 256, 0, stream>>>(x, xb);
    k_cast<<<3072, 256, 0, stream>>>(qkv_w, wqkv);
    k_cast<<<1024, 256, 0, stream>>>(proj_w, wproj);
    // qkv = x_c @ qkv_w^T, nan_to_num, -> bf16
    k_gemm_bt<true, false, true>
        <<<dim3(24, 32), 256, 0, stream>>>(xb, wqkv, (void*)qkvb, nullptr, 3072, 1024);
    k_post<<<dim3(32, HEADS, BATCH), 256, 0, stream>>>(qkvb, pe, q_scale, k_scale, qb, kb, vt);
    k_attn<<<dim3(SEQ / 64, BATCH * HEADS), 512, 0, stream>>>(qb, kb, vt, ao);
    // out = clip(attn_out) @ proj_w^T + proj_b (clip already applied in k_attn)
    k_gemm_bt<false, true, false>
        <<<dim3(8, 32), 256, 0, stream>>>(ao, wproj, (void*)out, proj_b, 1024, 1024);
}

// Round 7
// 155.010 us; speedup vs baseline: 1.0445x; 1.0445x over previous
//
#include <hip/hip_runtime.h>
#include <hip/hip_bf16.h>

#define DIMC 1024
#define HEADS 16
#define HD 64
#define BATCH 2
#define SEQ 2048

typedef __bf16 bf16;
typedef __bf16 bf16x4 __attribute__((ext_vector_type(4)));
typedef __bf16 bf16x8 __attribute__((ext_vector_type(8)));
typedef float f32x4 __attribute__((ext_vector_type(4)));

typedef const __attribute__((address_space(1))) void* gas_t;
typedef __attribute__((address_space(3))) void* las_t;

__device__ inline f32x4 mfma_bf16(bf16x8 a, bf16x8 b, f32x4 c) {
    return __builtin_amdgcn_mfma_f32_16x16x32_bf16(a, b, c, 0, 0, 0);
}

// store 8 bf16 to LDS as two b64 (row strides are 8B- but not 16B-aligned)
__device__ inline void st8(bf16* p, bf16x8 v) {
    *(bf16x4*)p       = *(bf16x4*)&v;
    *(bf16x4*)(p + 4) = *((bf16x4*)&v + 1);
}
// load one MFMA operand fragment: elements 0..3 at k, 4..7 at k+16
__device__ inline bf16x8 ld_frag(const bf16* p) {
    bf16x8 r;
    *(bf16x4*)&r       = *(const bf16x4*)p;
    *((bf16x4*)&r + 1) = *(const bf16x4*)(p + 16);
    return r;
}
// fragment read from a linear [*, 64] LDS tile with XOR-swizzled chunks:
// rowp = &tile[row*64]; cb = byte col (kk*64 + lg*8); sw = (row&7)<<4
__device__ inline bf16x8 ld_frag_s(const bf16* rowp, int cb, int sw) {
    bf16x8 r;
    *(bf16x4*)&r       = *(const bf16x4*)((const char*)rowp + ((cb) ^ sw));
    *((bf16x4*)&r + 1) = *(const bf16x4*)((const char*)rowp + ((cb + 32) ^ sw));
    return r;
}

// ---------------- prep: sanitize x + cast both weights, one launch --------
// flat float4 space: [0,1048576) x | [1048576,1835008) qkv_w | rest proj_w
__global__ __launch_bounds__(256) void k_prep_all(const float* __restrict__ x,
                                                  const float* __restrict__ qw,
                                                  const float* __restrict__ pw,
                                                  bf16* __restrict__ xb,
                                                  bf16* __restrict__ wqkv,
                                                  bf16* __restrict__ wproj) {
    int idx = blockIdx.x * 1024 + threadIdx.x;
#pragma unroll
    for (int j = 0; j < 4; ++j, idx += 256) {
        if (idx < 1048576) {
            float4 v = ((const float4*)x)[idx];
            float a[4] = {v.x, v.y, v.z, v.w};
            bf16x4 o;
#pragma unroll
            for (int q = 0; q < 4; ++q) {
                float f = a[q];
                f = __builtin_isfinite(f) ? fminf(fmaxf(f, -10000.f), 10000.f) : 0.f;
                o[q] = (bf16)f;
            }
            ((bf16x4*)xb)[idx] = o;
        } else if (idx < 1835008) {
            int i2 = idx - 1048576;
            float4 v = ((const float4*)qw)[i2];
            bf16x4 o = {(bf16)v.x, (bf16)v.y, (bf16)v.z, (bf16)v.w};
            ((bf16x4*)wqkv)[i2] = o;
        } else {
            int i2 = idx - 1835008;
            float4 v = ((const float4*)pw)[i2];
            bf16x4 o = {(bf16)v.x, (bf16)v.y, (bf16)v.z, (bf16)v.w};
            ((bf16x4*)wproj)[i2] = o;
        }
    }
}

// ---------------- generic GEMM (used for proj): C = A * Bt^T --------------
// m97 structure: 128x128 tile, BK=64, linear LDS + global_load_lds width=16,
// XOR-swizzled chunks. 4 waves (2x2), each wave 64x64.
template <bool OUT_BF16, bool BIAS, bool SANITIZE>
__global__ __launch_bounds__(256) void k_gemm_bt(const bf16* __restrict__ A,
                                                 const bf16* __restrict__ Bt,
                                                 void* __restrict__ Cv,
                                                 const float* __restrict__ bias,
                                                 int N, int K) {
    __shared__ alignas(16) bf16 As[128 * 64];
    __shared__ alignas(16) bf16 Bs[128 * 64];
    const int t = threadIdx.x;
    const int m0 = blockIdx.y * 128, n0 = blockIdx.x * 128;
    const int w = t >> 6, lane = t & 63;
    const int wm = (w >> 1) * 64, wn = (w & 1) * 64;
    const int lr = lane & 15, lg = lane >> 4;
    const int srow = lane >> 3;
    const int scol = ((lane & 7) ^ srow) * 8;
    const int sw = (lr & 7) << 4;

    f32x4 acc[4][4];
#pragma unroll
    for (int i = 0; i < 4; ++i)
#pragma unroll
        for (int j = 0; j < 4; ++j) acc[i][j] = 0.0f;

    for (int k0 = 0; k0 < K; k0 += 64) {
#pragma unroll
        for (int i = 0; i < 4; ++i) {
            int rg = w * 32 + i * 8;
            __builtin_amdgcn_global_load_lds(
                (gas_t)(A + (size_t)(m0 + rg + srow) * K + k0 + scol),
                (las_t)(As + rg * 64), 16, 0, 0);
            __builtin_amdgcn_global_load_lds(
                (gas_t)(Bt + (size_t)(n0 + rg + srow) * K + k0 + scol),
                (las_t)(Bs + rg * 64), 16, 0, 0);
        }
        __syncthreads();
#pragma unroll
        for (int kk = 0; kk < 2; ++kk) {
            const int cb = kk * 64 + lg * 8;
            bf16x8 af[4], bfr[4];
#pragma unroll
            for (int mi = 0; mi < 4; ++mi)
                af[mi] = ld_frag_s(&As[(wm + mi * 16 + lr) * 64], cb, sw);
#pragma unroll
            for (int ni = 0; ni < 4; ++ni)
                bfr[ni] = ld_frag_s(&Bs[(wn + ni * 16 + lr) * 64], cb, sw);
#pragma unroll
            for (int mi = 0; mi < 4; ++mi)
#pragma unroll
                for (int ni = 0; ni < 4; ++ni)
                    acc[mi][ni] = mfma_bf16(af[mi], bfr[ni], acc[mi][ni]);
        }
        __syncthreads();
    }
#pragma unroll
    for (int mi = 0; mi < 4; ++mi) {
#pragma unroll
        for (int ni = 0; ni < 4; ++ni) {
            int col = n0 + wn + ni * 16 + lr;
            float bval = BIAS ? bias[col] : 0.f;
#pragma unroll
            for (int r = 0; r < 4; ++r) {
                int row = m0 + wm + mi * 16 + lg * 4 + r;
                float v = acc[mi][ni][r];
                if (SANITIZE) v = __builtin_isfinite(v) ? v : 0.f;
                v += bval;
                if (OUT_BF16)
                    ((bf16*)Cv)[(size_t)row * N + col] = (bf16)v;
                else
                    ((float*)Cv)[(size_t)row * N + col] = v;
            }
        }
    }
}

// ---------------- qkv GEMM with fused rmsnorm+rope+v-transpose ------------
// Same K-loop as k_gemm_bt; epilogue: each wave's 64x64 tile = 64 seq rows
// x one full head of q, k, or v. q/k: per-row sum-sq (4 in-lane + 4 shfl),
// rsqrt, scale, RoPE (pair partner via shfl_xor(e,1), pe float2 per lane),
// write bf16 [B,H,L,D]. v: nan_to_num, write transposed [B,H,D,L] (bf16x4,
// 4 consecutive L per lane from the C/D layout). Kills k_post + qkvb.
__global__ __launch_bounds__(256) void k_gemm_qkv(const bf16* __restrict__ A,
                                                  const bf16* __restrict__ Bt,
                                                  const float* __restrict__ pe,
                                                  const float* __restrict__ q_scale,
                                                  const float* __restrict__ k_scale,
                                                  bf16* __restrict__ qb,
                                                  bf16* __restrict__ kb,
                                                  bf16* __restrict__ vt) {
    __shared__ alignas(16) bf16 As[128 * 64];
    __shared__ alignas(16) bf16 Bs[128 * 64];
    const int K = DIMC, t = threadIdx.x;
    const int m0 = blockIdx.y * 128, n0 = blockIdx.x * 128;
    const int w = t >> 6, lane = t & 63;
    const int wm = (w >> 1) * 64, wn = (w & 1) * 64;
    const int lr = lane & 15, lg = lane >> 4;
    const int srow = lane >> 3;
    const int scol = ((lane & 7) ^ srow) * 8;
    const int sw = (lr & 7) << 4;

    f32x4 acc[4][4];
#pragma unroll
    for (int i = 0; i < 4; ++i)
#pragma unroll
        for (int j = 0; j < 4; ++j) acc[i][j] = 0.0f;

    for (int k0 = 0; k0 < K; k0 += 64) {
#pragma unroll
        for (int i = 0; i < 4; ++i) {
            int rg = w * 32 + i * 8;
            __builtin_amdgcn_global_load_lds(
                (gas_t)(A + (size_t)(m0 + rg + srow) * K + k0 + scol),
                (las_t)(As + rg * 64), 16, 0, 0);
            __builtin_amdgcn_global_load_lds(
                (gas_t)(Bt + (size_t)(n0 + rg + srow) * K + k0 + scol),
                (las_t)(Bs + rg * 64), 16, 0, 0);
        }
        __syncthreads();
#pragma unroll
        for (int kk = 0; kk < 2; ++kk) {
            const int cb = kk * 64 + lg * 8;
            bf16x8 af[4], bfr[4];
#pragma unroll
            for (int mi = 0; mi < 4; ++mi)
                af[mi] = ld_frag_s(&As[(wm + mi * 16 + lr) * 64], cb, sw);
#pragma unroll
            for (int ni = 0; ni < 4; ++ni)
                bfr[ni] = ld_frag_s(&Bs[(wn + ni * 16 + lr) * 64], cb, sw);
#pragma unroll
            for (int mi = 0; mi < 4; ++mi)
#pragma unroll
                for (int ni = 0; ni < 4; ++ni)
                    acc[mi][ni] = mfma_bf16(af[mi], bfr[ni], acc[mi][ni]);
        }
        __syncthreads();
    }

    // ---- fused epilogue ----
    const int g = (n0 + wn) >> 6;          // head-slot 0..47
    const int sel = g >> 4;                // 0=q, 1=k, 2=v
    const int hh = g & 15;
    const int row0 = m0 + wm;              // global row base of wave tile
    const int bb = row0 >> 11;
    const int l0 = row0 & (SEQ - 1);
    const size_t bhh = (size_t)(bb * HEADS + hh);

    // nan_to_num (reference sanitizes qkv before norm/rope)
#pragma unroll
    for (int mi = 0; mi < 4; ++mi)
#pragma unroll
        for (int ni = 0; ni < 4; ++ni)
#pragma unroll
            for (int r = 0; r < 4; ++r) {
                float v = acc[mi][ni][r];
                acc[mi][ni][r] = __builtin_isfinite(v) ? v : 0.f;
            }

    if (sel == 2) {
        // V: write transposed [B,H,D,L]; 4 consecutive L per lane
#pragma unroll
        for (int mi = 0; mi < 4; ++mi)
#pragma unroll
            for (int ni = 0; ni < 4; ++ni) {
                bf16x4 ov;
#pragma unroll
                for (int r = 0; r < 4; ++r) ov[r] = (bf16)acc[mi][ni][r];
                *(bf16x4*)(vt + (bhh * HD + ni * 16 + lr) * SEQ +
                           l0 + mi * 16 + lg * 4) = ov;
            }
    } else {
        const float* sc = sel ? k_scale : q_scale;
        bf16* dst = sel ? kb : qb;
        // fold D^-0.5 * log2(e) into q
        const float oscale = sel ? 1.0f : 0.125f * 1.44269504088896340736f;
        float scv[4];
#pragma unroll
        for (int ni = 0; ni < 4; ++ni) scv[ni] = sc[ni * 16 + lr];
#pragma unroll
        for (int mi = 0; mi < 4; ++mi) {
#pragma unroll
            for (int r = 0; r < 4; ++r) {
                float ss = 0.f;
#pragma unroll
                for (int ni = 0; ni < 4; ++ni)
                    ss += acc[mi][ni][r] * acc[mi][ni][r];
                ss += __shfl_xor(ss, 1, 64);
                ss += __shfl_xor(ss, 2, 64);
                ss += __shfl_xor(ss, 4, 64);
                ss += __shfl_xor(ss, 8, 64);
                float rms = rsqrtf(ss * (1.f / 64.f) + 1e-6f);
                int l = l0 + mi * 16 + lg * 4 + r;
                const float* peb = pe + (size_t)l * 128 + (lr & 1) * 2;
                bf16* db = dst + (bhh * SEQ + l) * HD + lr;
#pragma unroll
                for (int ni = 0; ni < 4; ++ni) {
                    float e = acc[mi][ni][r] * rms * scv[ni];
                    float p = __shfl_xor(e, 1, 64);
                    float2 pv = *(const float2*)(peb + (ni * 8 + (lr >> 1)) * 4);
                    float ee = (lr & 1) ? p : e;
                    float eo = (lr & 1) ? e : p;
                    db[ni * 16] = (bf16)((pv.x * ee + pv.y * eo) * oscale);
                }
            }
        }
    }
}

// ---------------- flash attention (swapped QK^T, register P, O^T PV) ------
// grid (L/128 q-tiles, B*H), 512 threads = 8 waves, wave w -> q rows w*16..+16
// S^T = mfma(K, Q): lane holds S[q = w*16+(lane&15)][key = nk*16+(lane>>4)*4+r]
// l via ones-MFMA; defer-max THR=8 (exp2 domain); K/V double-buffered with
// early global-load issue (T14); one barrier per tile.
__global__ __launch_bounds__(512) void k_attn(const bf16* __restrict__ Q,
                                              const bf16* __restrict__ Kb,
                                              const bf16* __restrict__ Vt,
                                              bf16* __restrict__ O) {
    __shared__ bf16 Ks[2][64][68];
    __shared__ bf16 Vs[2][64][68];  // Vt tile: [d][key]
    const int qt = blockIdx.x, bh = blockIdx.y;
    const int b = bh >> 4, h = bh & 15;
    const int t = threadIdx.x, w = t >> 6, lane = t & 63;
    const int lr = lane & 15, lg = lane >> 4;
    const size_t baseQK = (size_t)bh * SEQ * HD;
    const size_t baseVt = (size_t)bh * HD * SEQ;

    // Q fragments straight from global (lane-private; 4 x 8B loads)
    const bf16* qp = Q + baseQK + (size_t)(qt * 128 + w * 16 + lr) * HD;
    bf16x8 qf0 = ld_frag(qp + lg * 4);
    bf16x8 qf1 = ld_frag(qp + 32 + lg * 4);

    const int sr = t >> 3, scol = (t & 7) * 8;  // staging coords (512 chunks)
    // stage K/V tile 0
    {
        bf16x8 kv = *(const bf16x8*)(Kb + baseQK + (size_t)sr * HD + scol);
        bf16x8 vv = *(const bf16x8*)(Vt + baseVt + (size_t)sr * SEQ + scol);
        st8(&Ks[0][sr][scol], kv);
        st8(&Vs[0][sr][scol], vv);
    }
    __syncthreads();

    bf16x8 ones;
#pragma unroll
    for (int j = 0; j < 8; ++j) ones[j] = (bf16)1.0f;

    f32x4 oacc[4];
#pragma unroll
    for (int i = 0; i < 4; ++i) oacc[i] = 0.0f;
    f32x4 lacc = 0.0f;
    float m_s = -1e30f;

    int cur = 0;
    for (int kt = 0; kt < SEQ / 64; ++kt) {
        // issue next tile's global loads early (latency hidden under compute)
        bf16x8 kreg, vreg;
        const bool pf = (kt + 1) < SEQ / 64;
        if (pf) {
            kreg = *(const bf16x8*)(Kb + baseQK + (size_t)((kt + 1) * 64 + sr) * HD + scol);
            vreg = *(const bf16x8*)(Vt + baseVt + (size_t)sr * SEQ + (kt + 1) * 64 + scol);
        }
        // QK^T on current tile
        __builtin_amdgcn_s_setprio(1);
        f32x4 s[4];
#pragma unroll
        for (int nk = 0; nk < 4; ++nk) {
            f32x4 a = 0.0f;
            a = mfma_bf16(ld_frag(&Ks[cur][nk * 16 + lr][lg * 4]), qf0, a);
            a = mfma_bf16(ld_frag(&Ks[cur][nk * 16 + lr][32 + lg * 4]), qf1, a);
            s[nk] = a;
        }
        __builtin_amdgcn_s_setprio(0);
        // row max: 16 in-lane + 2 shfls (q pre-scaled into exp2 domain)
        float tm = fmaxf(fmaxf(s[0][0], s[0][1]), fmaxf(s[0][2], s[0][3]));
#pragma unroll
        for (int nk = 1; nk < 4; ++nk)
            tm = fmaxf(tm, fmaxf(fmaxf(s[nk][0], s[nk][1]),
                                 fmaxf(s[nk][2], s[nk][3])));
        tm = fmaxf(tm, __shfl_xor(tm, 16, 64));
        tm = fmaxf(tm, __shfl_xor(tm, 32, 64));
        // defer-max: only rescale when some row grew past THR=8
        if (!__all(tm <= m_s + 8.f)) {
            float mnew = fmaxf(m_s, tm);
            float alpha = exp2f(m_s - mnew);
            m_s = mnew;
#pragma unroll
            for (int nd = 0; nd < 4; ++nd)
#pragma unroll
                for (int r2 = 0; r2 < 4; ++r2) oacc[nd][r2] *= alpha;
#pragma unroll
            for (int r2 = 0; r2 < 4; ++r2) lacc[r2] *= alpha;
        }
        // P (bounded by 2^8) packed straight into A-frag layout
        bf16x8 pa0, pa1;
#pragma unroll
        for (int j = 0; j < 4; ++j) {
            pa0[j]     = (bf16)exp2f(s[0][j] - m_s);
            pa0[4 + j] = (bf16)exp2f(s[1][j] - m_s);
            pa1[j]     = (bf16)exp2f(s[2][j] - m_s);
            pa1[4 + j] = (bf16)exp2f(s[3][j] - m_s);
        }
        __builtin_amdgcn_s_setprio(1);
        // l row-sum via ones-MFMA (lands in col q = lane&15, all regs equal)
        lacc = mfma_bf16(ones, pa0, lacc);
        lacc = mfma_bf16(ones, pa1, lacc);
#pragma unroll
        for (int nd = 0; nd < 4; ++nd) {
            oacc[nd] = mfma_bf16(ld_frag(&Vs[cur][nd * 16 + lr][lg * 4]), pa0, oacc[nd]);
            oacc[nd] = mfma_bf16(ld_frag(&Vs[cur][nd * 16 + lr][32 + lg * 4]), pa1, oacc[nd]);
        }
        __builtin_amdgcn_s_setprio(0);
        // write prefetched tile into the other buffer (readers synced at kt-1's barrier)
        if (pf) {
            st8(&Ks[cur ^ 1][sr][scol], kreg);
            st8(&Vs[cur ^ 1][sr][scol], vreg);
        }
        __syncthreads();
        cur ^= 1;
    }
    // epilogue: O^T[d][q] regs -> O[b, q, h*64+d], d = nd*16+lg*4+r (4 consecutive)
    {
        float inv = 1.f / lacc[0];
        int q = qt * 128 + w * 16 + lr;
#pragma unroll
        for (int nd = 0; nd < 4; ++nd) {
            bf16x4 ov;
#pragma unroll
            for (int r2 = 0; r2 < 4; ++r2) {
                float v = oacc[nd][r2] * inv;
                v = fminf(fmaxf(v, -10000.f), 10000.f);
                ov[r2] = (bf16)v;
            }
            *(bf16x4*)(O + ((size_t)(b * SEQ + q)) * DIMC + h * HD + nd * 16 + lg * 4) = ov;
        }
    }
}

extern "C" void kernel_launch(void* const* d_in, const int* in_sizes, int n_in,
                              void* d_out, int out_size, void* d_ws, size_t ws_size,
                              hipStream_t stream) {
    const float* x = (const float*)d_in[0];
    const float* pe = (const float*)d_in[1];
    const float* qkv_w = (const float*)d_in[2];
    const float* q_scale = (const float*)d_in[3];
    const float* k_scale = (const float*)d_in[4];
    const float* proj_w = (const float*)d_in[5];
    const float* proj_b = (const float*)d_in[6];
    float* out = (float*)d_out;
    char* ws = (char*)d_ws;

    // workspace layout (48 MB used)
    bf16* xb = (bf16*)(ws);                              // 8 MB  [4096][1024]
    bf16* wqkv = (bf16*)(ws + (8u << 20));               // 6 MB  [3072][1024]
    bf16* wproj = (bf16*)(ws + (14u << 20));             // 2 MB  [1024][1024]
    bf16* ao = (bf16*)(ws + (16u << 20));                // 8 MB  attn out bf16
    bf16* qb = (bf16*)(ws + (24u << 20));                // 8 MB  [B,H,L,D]
    bf16* kb = (bf16*)(ws + (32u << 20));                // 8 MB  [B,H,L,D]
    bf16* vt = (bf16*)(ws + (40u << 20));                // 8 MB  [B,H,D,L]

    k_prep_all<<<2048, 256, 0, stream>>>(x, qkv_w, proj_w, xb, wqkv, wproj);
    // qkv GEMM + fused nan_to_num/rmsnorm/rope/v-transpose
    k_gemm_qkv<<<dim3(24, 32), 256, 0, stream>>>(xb, wqkv, pe, q_scale, k_scale,
                                                 qb, kb, vt);
    k_attn<<<dim3(SEQ / 128, BATCH * HEADS), 512, 0, stream>>>(qb, kb, vt, ao);
    // out = attn_out @ proj_w^T + proj_b (clip already applied in k_attn)
    k_gemm_bt<false, true, false>
        <<<dim3(8, 32), 256, 0, stream>>>(ao, wproj, (void*)out, proj_b, 1024, 1024);
}